// Round 15
// baseline (162.875 us; speedup 1.0000x reference)
//
#include <hip/hip_runtime.h>

typedef __attribute__((ext_vector_type(8))) short bf16x8;
typedef __attribute__((ext_vector_type(4))) float f32x4;
typedef __attribute__((ext_vector_type(4))) unsigned int u32x4;
typedef unsigned short u16;
typedef unsigned int u32;

#define MFMA16(A, B, C) __builtin_amdgcn_mfma_f32_16x16x32_bf16((A), (B), (C), 0, 0, 0)

#if __has_builtin(__builtin_amdgcn_exp2f)
#define EXP2(x) __builtin_amdgcn_exp2f(x)
#else
#define EXP2(x) exp2f(x)
#endif

typedef __attribute__((address_space(3))) unsigned int lds_u32;
typedef const __attribute__((address_space(1))) unsigned int glb_u32;

__device__ __forceinline__ u16 f2bf(float f) {
  union { float f; unsigned u; } x; x.f = f;
  unsigned r = (x.u + 0x7fffu + ((x.u >> 16) & 1u)) >> 16;
  return (u16)r;
}
__device__ __forceinline__ float bf2f(u16 h) {
  union { float f; unsigned u; } x; x.u = ((unsigned)h) << 16;
  return x.f;
}

// K stager for flash (128-row tile): XOR-swizzled AND row-permuted so each
// lane's S-MFMA outputs land exactly on its PV A-fragment k-slots
// (k = ks*32 + quad*8 + j, ks = jt>>1) -> P stays in registers.
// LDS row (jt*16+p) holds global K-row (p>>2)*8+(jt&1)*4+(p&3)+(jt>>1)*32.
__device__ __forceinline__ void stage_swK128(const u16* src, u16* lds, int tid) {
#pragma unroll
  for (int i = 0; i < 4; i++) {
    int vv = tid + i * 256;
    int row = vv >> 3, c = vv & 7;          // LDS row 0..127, 16B chunk
    int p = row & 15, jt = row >> 4;        // jt 0..7
    int krow = ((p >> 2) << 3) + ((jt & 1) << 2) + (p & 3) + ((jt >> 1) << 5);
    const u16* gp = src + (size_t)krow * 64 + (size_t)(c ^ (row & 7)) * 8;
    __builtin_amdgcn_global_load_lds((glb_u32*)gp,
        (lds_u32*)(lds + (size_t)(i * 256 + (tid & 192)) * 8), 16, 0, 0);
  }
}

// V stager, linear 16KB (V' native 128-row/4-ks frag-packed layout).
__device__ __forceinline__ void stage_lin128(const u16* src, u16* lds, int tid) {
#pragma unroll
  for (int i = 0; i < 4; i++) {
    const u16* gp = src + (size_t)(i * 256 + tid) * 8;
    __builtin_amdgcn_global_load_lds((glb_u32*)gp,
        (lds_u32*)(lds + (size_t)(i * 256 + (tid & 192)) * 8), 16, 0, 0);
  }
}

template <int ROWS>
__device__ __forceinline__ void stage_ld512(const u16* src, u16* lds, int tid) {
#pragma unroll
  for (int i = 0; i < ROWS / 32; i++) {
    int vv = tid + i * 256;
    int row = vv >> 3, c = vv & 7;
    const u16* gp = src + (size_t)row * 512 + (size_t)(c ^ (row & 7)) * 8;
    __builtin_amdgcn_global_load_lds((glb_u32*)gp,
        (lds_u32*)(lds + (size_t)(i * 256 + (tid & 192)) * 8), 16, 0, 0);
  }
}

// ---------------- fused prep kernel ----------------
__global__ __launch_bounds__(256) void prep_kernel(const float* __restrict__ x,
                                                   u16* __restrict__ xb,
                                                   const float* __restrict__ Wa,
                                                   u16* __restrict__ wta,
                                                   const float* __restrict__ Wo,
                                                   u16* __restrict__ whi,
                                                   u16* __restrict__ wlo) {
  __shared__ u16 Th[64][72];
  __shared__ u16 Tl[64][72];
  const int bid = blockIdx.x;
  const int tid = threadIdx.x;

  if (bid < 4096) {
    int i = bid * 256 + tid;
    float4 v = ((const float4*)x)[i];
    ushort4 o;
    o.x = f2bf(v.x); o.y = f2bf(v.y); o.z = f2bf(v.z); o.w = f2bf(v.w);
    ((ushort4*)xb)[i] = o;
    return;
  }

  if (bid < 4288) {
    const int t = bid - 4096;
    const int n0 = (t % 24) * 64;
    const int k0 = (t / 24) * 64;
    const int r = tid >> 4, c4 = (tid & 15) * 4;
#pragma unroll
    for (int i = 0; i < 4; i++) {
      int row = r + i * 16;
      float4 v = *(const float4*)&Wa[(size_t)(k0 + row) * 1536 + n0 + c4];
      Th[c4 + 0][row] = f2bf(v.x);
      Th[c4 + 1][row] = f2bf(v.y);
      Th[c4 + 2][row] = f2bf(v.z);
      Th[c4 + 3][row] = f2bf(v.w);
    }
    __syncthreads();
    const int row = tid >> 2, c16 = (tid & 3) * 16;
    *(uint4*)&wta[(size_t)(n0 + row) * 512 + k0 + c16]     = *(uint4*)&Th[row][c16];
    *(uint4*)&wta[(size_t)(n0 + row) * 512 + k0 + c16 + 8] = *(uint4*)&Th[row][c16 + 8];
    return;
  }

  {
    const int t = bid - 4288;
    const int n0 = (t & 7) * 64;
    const int k0 = (t >> 3) * 64;
    const int r = tid >> 4, c4 = (tid & 15) * 4;
#pragma unroll
    for (int i = 0; i < 4; i++) {
      int row = r + i * 16;
      float4 v = *(const float4*)&Wo[(size_t)(k0 + row) * 512 + n0 + c4];
      float vv[4] = {v.x, v.y, v.z, v.w};
#pragma unroll
      for (int jj = 0; jj < 4; jj++) {
        u16 hi = f2bf(vv[jj]);
        Th[c4 + jj][row] = hi;
        Tl[c4 + jj][row] = f2bf(vv[jj] - bf2f(hi));
      }
    }
    __syncthreads();
    const int row = tid >> 2, c16 = (tid & 3) * 16;
    *(uint4*)&whi[(size_t)(n0 + row) * 512 + k0 + c16]     = *(uint4*)&Th[row][c16];
    *(uint4*)&whi[(size_t)(n0 + row) * 512 + k0 + c16 + 8] = *(uint4*)&Th[row][c16 + 8];
    *(uint4*)&wlo[(size_t)(n0 + row) * 512 + k0 + c16]     = *(uint4*)&Tl[row][c16];
    *(uint4*)&wlo[(size_t)(n0 + row) * 512 + k0 + c16 + 8] = *(uint4*)&Tl[row][c16 + 8];
  }
}

// ---------------- QKV GEMM (128x128 single-buf + coalesced epilogue) -----
__global__ __launch_bounds__(256) void gemm_qkv(const u16* __restrict__ xb,
                                                const u16* __restrict__ wta,
                                                const float* __restrict__ b_attn,
                                                u16* __restrict__ q,
                                                u16* __restrict__ kk,
                                                u16* __restrict__ v) {
  __shared__ u16 Smem[18432];  // [0,8192)=A, [8192,16384)=B, rest epilogue pad
  const int bid = blockIdx.x;
  const int xcd = bid & 7, rr = bid >> 3;       // rr in [0,96)
  const int m0 = (xcd * 8 + (rr & 7)) * 128;    // 64 m-tiles
  const int n0 = (rr >> 3) * 128;               // 12 n-tiles
  const int tid  = threadIdx.x;
  const int lane = tid & 63, w = tid >> 6;
  const int wm = w >> 1, wn = w & 1;
  const int quad = lane >> 4, l15 = lane & 15;
  const int sw0 = ((quad)     ^ (l15 & 7)) * 8;
  const int sw1 = ((quad + 4) ^ (l15 & 7)) * 8;

  f32x4 acc[4][4] = {};

  for (int kt = 0; kt < 8; kt++) {
    stage_ld512<128>(xb  + (size_t)m0 * 512 + kt * 64, Smem, tid);
    stage_ld512<128>(wta + (size_t)n0 * 512 + kt * 64, Smem + 8192, tid);
    __syncthreads();
#pragma unroll
    for (int ks = 0; ks < 2; ks++) {
      const int sw = ks ? sw1 : sw0;
      bf16x8 af[4], bf[4];
#pragma unroll
      for (int ri = 0; ri < 4; ri++)
        af[ri] = *(const bf16x8*)&Smem[(wm * 64 + ri * 16 + l15) * 64 + sw];
#pragma unroll
      for (int ci = 0; ci < 4; ci++)
        bf[ci] = *(const bf16x8*)&Smem[8192 + (wn * 64 + ci * 16 + l15) * 64 + sw];
#pragma unroll
      for (int ri = 0; ri < 4; ri++)
#pragma unroll
        for (int ci = 0; ci < 4; ci++)
          acc[ri][ci] = MFMA16(af[ri], bf[ci], acc[ri][ci]);
    }
    __syncthreads();
  }

  const float QS = 0.18033688011112043f;  // 0.125 * log2(e)
  const int wave_n0 = n0 + wn * 64;
  const int chunk = wave_n0 >> 9;
  const int h = (wave_n0 & 511) >> 6;
  const int m_wave = m0 + wm * 64;
  const int b = m_wave >> 11, t0 = m_wave & 2047;
  const int bh = b * 8 + h;

  if (chunk < 2) {
    u16* T = Smem + w * 4608;  // 64 x 72 per-wave scratch (post-barrier reuse)
    u16* dst = (chunk == 0) ? q : kk;
    const float scale = (chunk == 0) ? QS : 1.0f;
#pragma unroll
    for (int ri = 0; ri < 4; ri++)
#pragma unroll
      for (int ci = 0; ci < 4; ci++) {
        float bias = b_attn[wave_n0 + ci * 16 + l15];
#pragma unroll
        for (int r = 0; r < 4; r++) {
          int tl = ri * 16 + quad * 4 + r;
          T[tl * 72 + ci * 16 + l15] = f2bf((acc[ri][ci][r] + bias) * scale);
        }
      }
    u16* gdst = dst + (size_t)(bh * 2048 + t0 + lane) * 64;
#pragma unroll
    for (int j = 0; j < 8; j++)
      *(uint4*)&gdst[j * 8] = *(const uint4*)&T[lane * 72 + j * 8];
  } else {
#pragma unroll
    for (int ri = 0; ri < 4; ri++)
#pragma unroll
      for (int ci = 0; ci < 4; ci++) {
        int n = wave_n0 + ci * 16 + l15;
        float bias = b_attn[n];
        int d = n & 63;
        int tv = t0 + ri * 16 + quad * 4;
        int it = tv >> 7, ks2 = (tv >> 5) & 3, qd = (tv >> 3) & 3, jj = tv & 7;
        ushort4 pk;
        pk.x = f2bf(acc[ri][ci][0] + bias);
        pk.y = f2bf(acc[ri][ci][1] + bias);
        pk.z = f2bf(acc[ri][ci][2] + bias);
        pk.w = f2bf(acc[ri][ci][3] + bias);
        size_t idx = ((((size_t)bh * 16 + it) * 4 + ks2) * 64 + d) * 32 + qd * 8 + jj;
        *(ushort4*)&v[idx] = pk;
      }
  }
}

// ---------------- flash attention ----------------
// r15: KVBLK 64 -> 128. r14's in-register P left the per-iteration barrier
// convoy as the residual (32 sync events, each draining the K+V DMA). A
// 128-row K/V tile halves barrier count (16 iters) and doubles the compute
// covering each DMA. V' is natively packed in 128-row/4-ks tiles (gemm_qkv
// it = t0>>7), so this is its natural read granularity. The stage_swK128
// row permutation extends r14's formula to jt 0..7 / ks 0..3. LDS 64KB ->
// still 2 blocks/CU.
__global__ __launch_bounds__(256, 2) void flash_attn(const u16* __restrict__ q,
                                                     const u16* __restrict__ k,
                                                     const u16* __restrict__ vt,
                                                     u16* __restrict__ yb) {
  __shared__ u16 Kb[2][128 * 64];     // 32 KB (row-permuted + swizzled)
  __shared__ u16 Vb[2][128 * 64];     // 32 KB
  // total = 65536 B -> 2 blocks/CU

  const int flat = blockIdx.y * 16 + blockIdx.x;   // 512 blocks
  const int bh = (flat & 7) * 4 + ((flat >> 3) & 3);  // 4 bh per XCD band
  const int qt = flat >> 5;                        // 0..15, 128 q-rows each

  const int tid  = threadIdx.x;        // 0..255
  const int lane = tid & 63, w = tid >> 6;  // w in {0..3}
  const int quad = lane >> 4, l15 = lane & 15;
  const int sw0 = ((quad)     ^ (l15 & 7)) * 8;
  const int sw1 = ((quad + 4) ^ (l15 & 7)) * 8;

  const u16* qp = q  + (size_t)bh * 131072;
  const u16* kp = k  + (size_t)bh * 131072;
  const u16* vp = vt + (size_t)bh * 131072;

  // wave owns 32 q-rows: qt*128 + w*32 + qh*16 + l15
  bf16x8 qf[2][2];
#pragma unroll
  for (int qh = 0; qh < 2; qh++)
#pragma unroll
    for (int ks = 0; ks < 2; ks++)
      qf[qh][ks] = *(const bf16x8*)(qp + (size_t)(qt * 128 + w * 32 + qh * 16 + l15) * 64 + ks * 32 + quad * 8);

  f32x4 l_acc[2] = {};
  f32x4 o[2][4] = {};

  bf16x8 ones;
  {
    short one = (short)0x3F80;
    ones = (bf16x8){one, one, one, one, one, one, one, one};
  }

  stage_swK128(kp, Kb[0], tid);
  stage_lin128(vp, Vb[0], tid);

  for (int it = 0; it < 16; it++) {
    __syncthreads();   // K[it],V[it] landed; prior reads of overwritten bufs done
    if (it < 15) {
      stage_swK128(kp + (size_t)(it + 1) * 8192, Kb[(it + 1) & 1], tid);
      stage_lin128(vp + (size_t)(it + 1) * 8192, Vb[(it + 1) & 1], tid);
    }
    const u16* Kc = Kb[it & 1];
    const u16* Vc = Vb[it & 1];

    // S phase: K rows pre-permuted -> lane's outputs ARE its PV fragment.
    // pa[qh][ks] = P[q=l15][k = ks*32 + quad*8 + (0..7)], ks = jt>>1.
    u32x4 pa[2][4];
#pragma unroll
    for (int jt = 0; jt < 8; jt++) {
      bf16x8 kf0 = *(const bf16x8*)&Kc[(jt * 16 + l15) * 64 + sw0];
      bf16x8 kf1 = *(const bf16x8*)&Kc[(jt * 16 + l15) * 64 + sw1];
#pragma unroll
      for (int qh = 0; qh < 2; qh++) {
        f32x4 s = {0.f, 0.f, 0.f, 0.f};
        s = MFMA16(kf0, qf[qh][0], s);
        s = MFMA16(kf1, qf[qh][1], s);
        u32 pb[4];
#pragma unroll
        for (int r = 0; r < 4; r++) pb[r] = __float_as_uint(EXP2(s[r]));
        pa[qh][jt >> 1][(jt & 1) * 2 + 0] = __builtin_amdgcn_perm(pb[1], pb[0], 0x07060302u);
        pa[qh][jt >> 1][(jt & 1) * 2 + 1] = __builtin_amdgcn_perm(pb[3], pb[2], 0x07060302u);
      }
    }

    // PV phase: P from registers, V from LDS (native frag-packed layout)
    __builtin_amdgcn_s_setprio(1);
#pragma unroll
    for (int ks = 0; ks < 4; ks++) {
      bf16x8 pf0 = __builtin_bit_cast(bf16x8, pa[0][ks]);
      bf16x8 pf1 = __builtin_bit_cast(bf16x8, pa[1][ks]);
      l_acc[0] = MFMA16(pf0, ones, l_acc[0]);
      l_acc[1] = MFMA16(pf1, ones, l_acc[1]);
#pragma unroll
      for (int dt = 0; dt < 4; dt++) {
        bf16x8 vf = *(const bf16x8*)&Vc[ks * 2048 + (dt * 16 + l15) * 32 + quad * 8];
        o[0][dt] = MFMA16(pf0, vf, o[0][dt]);
        o[1][dt] = MFMA16(pf1, vf, o[1][dt]);
      }
    }
    __builtin_amdgcn_s_setprio(0);
  }

  __syncthreads();  // all waves done with Kb/Vb; safe to reuse K region

  // epilogue per q-half: normalize, LDS transpose (K-region scratch), store
  const int b = bh >> 3, h = bh & 7;
  u32* Tw = (u32*)(&Kb[0][0]) + (size_t)w * 1088;  // 16 x 68 u32 per wave
#pragma unroll
  for (int qh = 0; qh < 2; qh++) {
#pragma unroll
    for (int r = 0; r < 4; r++) {
      float inv = 1.f / l_acc[qh][r];
#pragma unroll
      for (int dt = 0; dt < 4; dt++) {
        float val = o[qh][dt][r] * inv;
        u16 hi = f2bf(val);
        u16 lo = f2bf(val - bf2f(hi));
        Tw[(quad * 4 + r) * 68 + dt * 16 + l15] = (u32)hi | ((u32)lo << 16);
      }
    }
    int t = qt * 128 + w * 32 + qh * 16 + l15;
    size_t rowb = (size_t)(b * 2048 + t) * 512 + h * 64 + quad * 16;
    uint4 g0 = *(uint4*)&Tw[l15 * 68 + quad * 16 + 0];
    uint4 g1 = *(uint4*)&Tw[l15 * 68 + quad * 16 + 4];
    uint4 g2 = *(uint4*)&Tw[l15 * 68 + quad * 16 + 8];
    uint4 g3 = *(uint4*)&Tw[l15 * 68 + quad * 16 + 12];
    uint4 hi4, lo4;
    hi4.x = __builtin_amdgcn_perm(g0.y, g0.x, 0x05040100u);
    hi4.y = __builtin_amdgcn_perm(g0.w, g0.z, 0x05040100u);
    hi4.z = __builtin_amdgcn_perm(g1.y, g1.x, 0x05040100u);
    hi4.w = __builtin_amdgcn_perm(g1.w, g1.z, 0x05040100u);
    lo4.x = __builtin_amdgcn_perm(g0.y, g0.x, 0x07060302u);
    lo4.y = __builtin_amdgcn_perm(g0.w, g0.z, 0x07060302u);
    lo4.z = __builtin_amdgcn_perm(g1.y, g1.x, 0x07060302u);
    lo4.w = __builtin_amdgcn_perm(g1.w, g1.z, 0x07060302u);
    *(uint4*)&yb[rowb] = hi4;
    *(uint4*)&yb[(size_t)4 * 2048 * 512 + rowb] = lo4;
    hi4.x = __builtin_amdgcn_perm(g2.y, g2.x, 0x05040100u);
    hi4.y = __builtin_amdgcn_perm(g2.w, g2.z, 0x05040100u);
    hi4.z = __builtin_amdgcn_perm(g3.y, g3.x, 0x05040100u);
    hi4.w = __builtin_amdgcn_perm(g3.w, g3.z, 0x05040100u);
    lo4.x = __builtin_amdgcn_perm(g2.y, g2.x, 0x07060302u);
    lo4.y = __builtin_amdgcn_perm(g2.w, g2.z, 0x07060302u);
    lo4.z = __builtin_amdgcn_perm(g3.y, g3.x, 0x07060302u);
    lo4.w = __builtin_amdgcn_perm(g3.w, g3.z, 0x07060302u);
    *(uint4*)&yb[rowb + 8] = hi4;
    *(uint4*)&yb[(size_t)4 * 2048 * 512 + rowb + 8] = lo4;
  }
}

// ---------------- output projection (128x64 m97 structure) ---------------
__global__ __launch_bounds__(256) void gemm_out(const u16* __restrict__ yhi,
                                                const u16* __restrict__ ylo,
                                                const u16* __restrict__ whi,
                                                const u16* __restrict__ wlo,
                                                const float* __restrict__ b_out,
                                                float* __restrict__ out) {
  __shared__ u16 Ah[128 * 64];
  __shared__ u16 Al[128 * 64];
  __shared__ u16 Bh[64 * 64];
  __shared__ u16 Bl[64 * 64];
  const int bid = blockIdx.x;
  const int xcd = bid & 7, rr = bid >> 3;       // rr in [0,64)
  const int m0 = (xcd * 8 + (rr & 7)) * 128;    // 64 m-tiles
  const int n0 = (rr >> 3) * 64;                // 8 n-tiles
  const int tid  = threadIdx.x;
  const int lane = tid & 63, w = tid >> 6;
  const int wm = w >> 1, wn = w & 1;
  const int quad = lane >> 4, l15 = lane & 15;
  const int sw0 = ((quad)     ^ (l15 & 7)) * 8;
  const int sw1 = ((quad + 4) ^ (l15 & 7)) * 8;

  f32x4 acc[4][2] = {};

  for (int kt = 0; kt < 8; kt++) {
    const int k0 = kt * 64;
    stage_ld512<128>(yhi + (size_t)m0 * 512 + k0, Ah, tid);
    stage_ld512<128>(ylo + (size_t)m0 * 512 + k0, Al, tid);
    stage_ld512<64>(whi + (size_t)n0 * 512 + k0, Bh, tid);
    stage_ld512<64>(wlo + (size_t)n0 * 512 + k0, Bl, tid);
    __syncthreads();
#pragma unroll
    for (int ks = 0; ks < 2; ks++) {
      const int sw = ks ? sw1 : sw0;
      bf16x8 afh[4], afl[4], bfh[2], bfl[2];
#pragma unroll
      for (int ri = 0; ri < 4; ri++) {
        afh[ri] = *(const bf16x8*)&Ah[(wm * 64 + ri * 16 + l15) * 64 + sw];
        afl[ri] = *(const bf16x8*)&Al[(wm * 64 + ri * 16 + l15) * 64 + sw];
      }
#pragma unroll
      for (int ci = 0; ci < 2; ci++) {
        bfh[ci] = *(const bf16x8*)&Bh[(wn * 32 + ci * 16 + l15) * 64 + sw];
        bfl[ci] = *(const bf16x8*)&Bl[(wn * 32 + ci * 16 + l15) * 64 + sw];
      }
#pragma unroll
      for (int ri = 0; ri < 4; ri++)
#pragma unroll
        for (int ci = 0; ci < 2; ci++) {
          acc[ri][ci] = MFMA16(afh[ri], bfh[ci], acc[ri][ci]);
          acc[ri][ci] = MFMA16(afh[ri], bfl[ci], acc[ri][ci]);
          acc[ri][ci] = MFMA16(afl[ri], bfh[ci], acc[ri][ci]);
        }
    }
    __syncthreads();
  }

#pragma unroll
  for (int ri = 0; ri < 4; ri++) {
#pragma unroll
    for (int ci = 0; ci < 2; ci++) {
      int n = n0 + wn * 32 + ci * 16 + l15;
      float bias = b_out[n];
#pragma unroll
      for (int r = 0; r < 4; r++) {
        int m = m0 + wm * 64 + ri * 16 + quad * 4 + r;
        out[(size_t)m * 512 + n] = acc[ri][ci][r] + bias;
      }
    }
  }
}

// ---------------- launch ----------------
extern "C" void kernel_launch(void* const* d_in, const int* in_sizes, int n_in,
                              void* d_out, int out_size, void* d_ws, size_t ws_size,
                              hipStream_t stream) {
  const float* x      = (const float*)d_in[0];
  const float* W_attn = (const float*)d_in[1];
  const float* b_attn = (const float*)d_in[2];
  const float* W_out  = (const float*)d_in[3];
  const float* b_out  = (const float*)d_in[4];
  float* out = (float*)d_out;

  char* ws = (char*)d_ws;
  u16* xb   = (u16*)(ws + 0);                 //  8 MB  [8192][512]
  u16* wta  = (u16*)(ws + 8388608);           //  1.5MB [1536][512]
  u16* wtoh = (u16*)(ws + 9961472);           //  0.5MB [512][512]
  u16* wtol = (u16*)(ws + 10485760);          //  0.5MB
  u16* qb   = (u16*)(ws + 11010048);          //  8 MB  [bh][t][64] (pre-scaled)
  u16* kb   = (u16*)(ws + 19398656);          //  8 MB  [bh][t][64]
  u16* vtb  = (u16*)(ws + 27787264);          //  8 MB  V' frag-packed
  u16* yhi  = (u16*)(ws + 36175872);          //  8 MB  [B,T,C] (+8 MB lo plane)

  prep_kernel<<<4352, 256, 0, stream>>>(x, xb, W_attn, wta, W_out, wtoh, wtol);
  gemm_qkv<<<768, 256, 0, stream>>>(xb, wta, b_attn, qb, kb, vtb);
  flash_attn<<<dim3(16, 32), 256, 0, stream>>>(qb, kb, vtb, yhi);
  gemm_out<<<512, 256, 0, stream>>>(yhi, yhi + (size_t)4 * 2048 * 512, wtoh, wtol, b_out, out);
}